// Round 1
// baseline (629.558 us; speedup 1.0000x reference)
//
#include <hip/hip_runtime.h>

typedef unsigned short ushort_t;
typedef short short8 __attribute__((ext_vector_type(8)));
typedef float f32x4 __attribute__((ext_vector_type(4)));
typedef unsigned short ushort4v __attribute__((ext_vector_type(4)));

// ---------- helpers ----------
__device__ __forceinline__ ushort_t f2bf(float f) {
    unsigned int u = __float_as_uint(f);
    u = (u + 0x7fffu + ((u >> 16) & 1u)) >> 16;
    return (ushort_t)u;
}

__device__ __forceinline__ void async16(void* lds, const void* g) {
    __builtin_amdgcn_global_load_lds(
        (const __attribute__((address_space(1))) unsigned int*)g,
        (__attribute__((address_space(3))) unsigned int*)lds, 16, 0, 0);
}

// ---------- prep kernels ----------
__global__ void conv_x_kernel(const float* __restrict__ in, ushort_t* __restrict__ out) {
    int i = blockIdx.x * 256 + threadIdx.x;      // grid sized exactly: 50176*256 = 12845056
    float4 v = ((const float4*)in)[i];
    ushort4v o;
    o.x = f2bf(v.x); o.y = f2bf(v.y); o.z = f2bf(v.z); o.w = f2bf(v.w);
    ((ushort4v*)out)[i] = o;
}

__global__ void prep_weights(const float* __restrict__ qkv_w, const float* __restrict__ proj_w,
                             ushort_t* __restrict__ wtq, ushort_t* __restrict__ wtp) {
    int o = blockIdx.x * 256 + threadIdx.x;      // grid 3072*256 = 786432
    if (o < 1536 * 512) {
        int n = o >> 9, k = o & 511;
        wtq[o] = f2bf(qkv_w[k * 1536 + n]);      // wtq[n][k] = W[k][n]
    }
    if (o < 512 * 512) {
        int n = o >> 9, k = o & 511;
        wtp[o] = f2bf(proj_w[k * 512 + n]);
    }
}

__global__ void build_cm(const float* __restrict__ mask, const float* __restrict__ rel_table,
                         const int* __restrict__ rel_index, float* __restrict__ cm) {
    int o = blockIdx.x * 256 + threadIdx.x;      // grid 16384*256 = 4194304 = 64*16*64*64
    int c = o & 63, r = (o >> 6) & 63, h = (o >> 12) & 15, w = o >> 16;
    float v = -30000.0f;
    if (r < 49 && c < 49)
        v = rel_table[rel_index[r * 49 + c] * 16 + h] + mask[w * 2401 + r * 49 + c];
    cm[o] = v;
}

// ---------- bf16 MFMA GEMM: C[M][N] = A[M][K] * Bt[N][K]^T + bias ----------
// m97-style: 128x128 tile, BK=32, 4 waves, global_load_lds staging, 16x16x32 MFMA.
template<int NSTR, bool QKV>
__global__ __launch_bounds__(256, 2)
void gemm_bt(const ushort_t* __restrict__ A, const ushort_t* __restrict__ Bt,
             const float* __restrict__ bias, void* __restrict__ out,
             int M, int K)
{
    __shared__ alignas(16) ushort_t As[128 * 32];
    __shared__ alignas(16) ushort_t Bs[128 * 32];
    const int tid = threadIdx.x;
    const int wid = tid >> 6;
    const int lane = tid & 63;
    const int lr = lane & 15;
    const int lk = lane >> 4;
    const int m0 = blockIdx.x << 7;
    const int n0 = blockIdx.y << 7;
    const int wr = (wid >> 1) << 6;
    const int wc = (wid & 1) << 6;

    f32x4 acc[4][4];
#pragma unroll
    for (int i = 0; i < 4; ++i)
#pragma unroll
        for (int j = 0; j < 4; ++j)
#pragma unroll
            for (int r = 0; r < 4; ++r) acc[i][j][r] = 0.f;

    const int KT = K >> 5;
    for (int kt = 0; kt < KT; ++kt) {
        const int kb = kt << 5;
#pragma unroll
        for (int t = 0; t < 2; ++t) {
            const int cb = t * 256 + wid * 64;   // wave-uniform chunk base
            const int c = cb + lane;
            async16((char*)As + cb * 16, A + (size_t)(m0 + (c >> 2)) * K + kb + (c & 3) * 8);
            async16((char*)Bs + cb * 16, Bt + (size_t)(n0 + (c >> 2)) * K + kb + (c & 3) * 8);
        }
        __syncthreads();   // drains vmcnt before barrier (compiler-enforced)
        short8 af[4], bf[4];
#pragma unroll
        for (int i = 0; i < 4; ++i) af[i] = *(const short8*)&As[(wr + i * 16 + lr) * 32 + lk * 8];
#pragma unroll
        for (int j = 0; j < 4; ++j) bf[j] = *(const short8*)&Bs[(wc + j * 16 + lr) * 32 + lk * 8];
#pragma unroll
        for (int i = 0; i < 4; ++i)
#pragma unroll
            for (int j = 0; j < 4; ++j)
                acc[i][j] = __builtin_amdgcn_mfma_f32_16x16x32_bf16(af[i], bf[j], acc[i][j], 0, 0, 0);
        __syncthreads();
    }

#pragma unroll
    for (int j = 0; j < 4; ++j) {
        const int col = n0 + wc + j * 16 + lr;
        const float bv = bias[col];
#pragma unroll
        for (int i = 0; i < 4; ++i) {
#pragma unroll
            for (int r = 0; r < 4; ++r) {
                const int row = m0 + wr + i * 16 + lk * 4 + r;
                float v = acc[i][j][r] + bv;
                if (QKV) {
                    if (col < 512) v *= 0.17677669529663689f;   // (x@W+b) * head_dim^-0.5 on q
                    ((ushort_t*)out)[(size_t)row * NSTR + col] = f2bf(v);
                } else {
                    ((float*)out)[(size_t)row * NSTR + col] = v;
                }
            }
        }
    }
}

// ---------- fused window attention: one wave per (b,h) ----------
// qkv: [100352][1536] bf16 (q pre-scaled, bias added). cm: [64][16][64][64] f32.
// out: [100352][512] bf16  (out[b*49+n][h*32+d])
#define PL_STRIDE 80   // bf16 elems; 160B rows -> 16B aligned
#define VT_STRIDE 88   // bf16 elems; 176B rows -> 16B aligned, low bank conflict
__global__ __launch_bounds__(256, 2)
void attn_kernel(const ushort_t* __restrict__ qkv, const float* __restrict__ cm,
                 ushort_t* __restrict__ out)
{
    // Pl region (40960B) is unioned with the cm tile (16640B); vT separate (22528B).
    __shared__ alignas(16) char smem[4 * 64 * PL_STRIDE * 2 + 4 * 32 * VT_STRIDE * 2];
    float* cmf = (float*)smem;                                    // [64][65]
    ushort_t* Pl = (ushort_t*)smem;                               // [4][64][PL_STRIDE]
    ushort_t* vT = (ushort_t*)(smem + 4 * 64 * PL_STRIDE * 2);    // [4][32][VT_STRIDE]

    const int w = blockIdx.x, h = blockIdx.y, ig = blockIdx.z;
    const int tid = threadIdx.x;
    const int wid = tid >> 6, lane = tid & 63;
    const int lr = lane & 15, lk = lane >> 4;
    const int b = (ig * 4 + wid) * 64 + w;       // b % 64 == w (mask window index)

    // stage cm[w][h] tile into LDS (shared by the 4 waves)
    const float* cmsrc = cm + ((size_t)(w * 16 + h) << 12);
    for (int t = tid; t < 4096; t += 256)
        cmf[(t >> 6) * 65 + (t & 63)] = cmsrc[t];
    __syncthreads();

    const size_t base = (size_t)b * 49 * 1536 + h * 32;

    // q/k fragments (rows padded 49->64 via clamp; garbage killed by cm = -30000)
    short8 aq[4], bk[4];
#pragma unroll
    for (int i = 0; i < 4; ++i) {
        int n = i * 16 + lr; n = n > 48 ? 48 : n;
        aq[i] = *(const short8*)&qkv[base + (size_t)n * 1536 + lk * 8];
    }
#pragma unroll
    for (int j = 0; j < 4; ++j) {
        int m = j * 16 + lr; m = m > 48 ? 48 : m;
        bk[j] = *(const short8*)&qkv[base + 512 + (size_t)m * 1536 + lk * 8];
    }

    f32x4 s[4][4];
#pragma unroll
    for (int i = 0; i < 4; ++i)
#pragma unroll
        for (int j = 0; j < 4; ++j)
#pragma unroll
            for (int r = 0; r < 4; ++r) s[i][j][r] = 0.f;
#pragma unroll
    for (int i = 0; i < 4; ++i)
#pragma unroll
        for (int j = 0; j < 4; ++j)
            s[i][j] = __builtin_amdgcn_mfma_f32_16x16x32_bf16(aq[i], bk[j], s[i][j], 0, 0, 0);

    // v load (row m = lane) and transposed LDS store vT[d][m]
    short8 vv[4];
#pragma unroll
    for (int t = 0; t < 4; ++t)
#pragma unroll
        for (int e = 0; e < 8; ++e) vv[t][e] = 0;
    if (lane < 49) {
        const ushort_t* vp = &qkv[base + 1024 + (size_t)lane * 1536];
#pragma unroll
        for (int t = 0; t < 4; ++t) vv[t] = *(const short8*)(vp + t * 8);
    }
    ushort_t* vTw = vT + wid * 32 * VT_STRIDE;
#pragma unroll
    for (int t = 0; t < 4; ++t)
#pragma unroll
        for (int e = 0; e < 8; ++e)
            vTw[(t * 8 + e) * VT_STRIDE + lane] = (ushort_t)vv[t][e];

    // add bias+mask, wave-parallel online-free softmax (rows are (lk*4+r)+16i, cols lane-spread)
#pragma unroll
    for (int i = 0; i < 4; ++i) {
#pragma unroll
        for (int r = 0; r < 4; ++r) {
            const int row = i * 16 + lk * 4 + r;
            float v0 = s[i][0][r] + cmf[row * 65 + lr];
            float v1 = s[i][1][r] + cmf[row * 65 + 16 + lr];
            float v2 = s[i][2][r] + cmf[row * 65 + 32 + lr];
            float v3 = s[i][3][r] + cmf[row * 65 + 48 + lr];
            float mx = fmaxf(fmaxf(v0, v1), fmaxf(v2, v3));
#pragma unroll
            for (int t = 1; t < 16; t <<= 1) mx = fmaxf(mx, __shfl_xor(mx, t, 64));
            v0 = __expf(v0 - mx); v1 = __expf(v1 - mx);
            v2 = __expf(v2 - mx); v3 = __expf(v3 - mx);
            float sm = v0 + v1 + v2 + v3;
#pragma unroll
            for (int t = 1; t < 16; t <<= 1) sm += __shfl_xor(sm, t, 64);
            const float inv = 1.0f / sm;
            s[i][0][r] = v0 * inv; s[i][1][r] = v1 * inv;
            s[i][2][r] = v2 * inv; s[i][3][r] = v3 * inv;
        }
    }
    __syncthreads();   // all waves done reading cm tile; safe to overwrite with P

    // P -> bf16 -> LDS (per-wave slice)
    ushort_t* Pw = Pl + wid * 64 * PL_STRIDE;
#pragma unroll
    for (int i = 0; i < 4; ++i)
#pragma unroll
        for (int j = 0; j < 4; ++j)
#pragma unroll
            for (int r = 0; r < 4; ++r)
                Pw[(i * 16 + lk * 4 + r) * PL_STRIDE + j * 16 + lr] = f2bf(s[i][j][r]);

    // PV: out[n][d] = sum_m P[n][m] * v[m][d]
    f32x4 o[4][2];
#pragma unroll
    for (int i = 0; i < 4; ++i)
#pragma unroll
        for (int jb = 0; jb < 2; ++jb)
#pragma unroll
            for (int r = 0; r < 4; ++r) o[i][jb][r] = 0.f;
#pragma unroll
    for (int ks = 0; ks < 2; ++ks) {
        short8 pa[4], vb[2];
#pragma unroll
        for (int i = 0; i < 4; ++i)
            pa[i] = *(const short8*)&Pw[(i * 16 + lr) * PL_STRIDE + ks * 32 + lk * 8];
#pragma unroll
        for (int jb = 0; jb < 2; ++jb)
            vb[jb] = *(const short8*)&vTw[(jb * 16 + lr) * VT_STRIDE + ks * 32 + lk * 8];
#pragma unroll
        for (int i = 0; i < 4; ++i)
#pragma unroll
            for (int jb = 0; jb < 2; ++jb)
                o[i][jb] = __builtin_amdgcn_mfma_f32_16x16x32_bf16(pa[i], vb[jb], o[i][jb], 0, 0, 0);
    }

    // write attn output (bf16) as [b*49+n][h*32+d]
    const size_t obase = (size_t)b * 49 * 512 + h * 32;
#pragma unroll
    for (int i = 0; i < 4; ++i) {
#pragma unroll
        for (int r = 0; r < 4; ++r) {
            const int n = i * 16 + lk * 4 + r;
            if (n < 49) {
#pragma unroll
                for (int jb = 0; jb < 2; ++jb)
                    out[obase + (size_t)n * 512 + jb * 16 + lr] = f2bf(o[i][jb][r]);
            }
        }
    }
}

// ---------- launch ----------
extern "C" void kernel_launch(void* const* d_in, const int* in_sizes, int n_in,
                              void* d_out, int out_size, void* d_ws, size_t ws_size,
                              hipStream_t stream)
{
    const float* x         = (const float*)d_in[0];
    const float* mask      = (const float*)d_in[1];
    const float* qkv_w     = (const float*)d_in[2];
    const float* qkv_b     = (const float*)d_in[3];
    const float* proj_w    = (const float*)d_in[4];
    const float* proj_b    = (const float*)d_in[5];
    const float* rel_table = (const float*)d_in[6];
    const int*   rel_index = (const int*)d_in[7];

    char* ws = (char*)d_ws;
    ushort_t* xb  = (ushort_t*)ws;                      // x bf16 / attn-out reuse: 102,760,448 B
    ushort_t* qkv = (ushort_t*)(ws + 102760448);        // 308,281,344 B
    ushort_t* wtq = (ushort_t*)(ws + 411041792);        // 1,572,864 B
    ushort_t* wtp = (ushort_t*)(ws + 412614656);        // 524,288 B
    float*    cm  = (float*)  (ws + 413138944);         // 16,777,216 B (total ~430 MB)

    conv_x_kernel<<<50176, 256, 0, stream>>>(x, xb);
    prep_weights<<<3072, 256, 0, stream>>>(qkv_w, proj_w, wtq, wtp);
    build_cm<<<16384, 256, 0, stream>>>(mask, rel_table, rel_index, cm);

    // QKV GEMM: [100352,512] x [512,1536] -> qkv bf16 (q pre-scaled)
    gemm_bt<1536, true><<<dim3(784, 12), 256, 0, stream>>>(xb, wtq, qkv_b, qkv, 100352, 512);

    // attention: grid (window, head, image-group), 4 waves/block
    attn_kernel<<<dim3(64, 16, 8), 256, 0, stream>>>(qkv, cm, xb);

    // proj GEMM: [100352,512] x [512,512] -> d_out f32
    gemm_bt<512, false><<<dim3(784, 4), 256, 0, stream>>>(xb, wtp, proj_b, d_out, 100352, 512);
}